// Round 3
// baseline (33674.512 us; speedup 1.0000x reference)
//
#include <hip/hip_runtime.h>
#include <math.h>

// Persistent cooperative LSTM: 256 WGs x 512 threads, 1 WG/CU.
// WG w owns hidden units [8w, 8w+8). wave u = unit, 16-lane group g = gate.
// Folded weights W' = W_hh + (w1+w2) (x) W_lin in regs (128/thread).
//
// Sync (zero barriers per step):
//   producer lane0: store packed ((t+1)<<32 | f32bits(h)) to h_buf[t&1][unit]
//   wave w pulls chunk w (256 units) with throttled polls (s_sleep), writes
//   h_lds[t&1], sets LDS flag ready[t&1][w]=t+1 (release).
//   step t+1 matvec spins each chunk flag (acquire) just before consuming it.
// Race-freedom of buffer reuse follows transitively: a wave can only reach
// its step-(t+2) pull (overwriting buf[t&1]) after all chunk flags of step
// t+1 are set, which requires every wave to have finished reading buf[t&1].
//
// y_t: owner WG (t%256) accumulates per-wave partials from the pulled
// registers (ds_add to y_acc), wave 7 finalizes during step t+1's chunk wait.

#define HDIM 2048
#define TSTEPS 4096
#define NWG 256
#define NTH 512  // 8 waves

typedef unsigned long long u64;

__device__ __forceinline__ float sigmoidf_(float x) {
    return 1.0f / (1.0f + expf(-x));
}

__global__ __launch_bounds__(NTH, 2)
void weld_lstm_persistent(const float* __restrict__ src,
                          const float* __restrict__ W_ih,
                          const float* __restrict__ W_hh,
                          const float* __restrict__ b_ih,
                          const float* __restrict__ b_hh,
                          const float* __restrict__ W_lin,
                          const float* __restrict__ b_lin,
                          float* __restrict__ out,
                          u64* __restrict__ h_buf)
{
    __shared__ float h_lds[2][HDIM];   // double-buffered h (8 KiB each)
    __shared__ float s_lds[TSTEPS];    // 16 KiB: src[0,t,0]
    __shared__ float wlin_lds[HDIM];   // 8 KiB
    __shared__ int   ready[2][8];      // per-(parity, chunk) step tags
    __shared__ float y_acc[2];         // y partial accumulator per parity

    const int wg   = blockIdx.x;       // 0..255
    const int tid  = threadIdx.x;      // 0..511
    const int wave = tid >> 6;         // 0..7: owned unit index AND pull chunk
    const int lane = tid & 63;
    const int g    = lane >> 4;        // gate 0..3 (i,f,g,o)
    const int sub  = lane & 15;        // column-slice within row
    const int unit = wg * 8 + wave;
    const int row  = g * HDIM + unit;

    // ---- one-time init ----
    for (int i = tid; i < TSTEPS; i += NTH) s_lds[i] = src[3 * i];
    for (int i = tid; i < HDIM;   i += NTH) wlin_lds[i] = W_lin[i];
    if (tid < 16) ready[tid >> 3][tid & 7] = 0;
    if (tid < 2)  y_acc[tid] = 0.0f;

    const float s01  = src[1];
    const float s02  = src[2];
    const float blin = b_lin[0];

    const float w0    = W_ih[row * 3 + 0];
    const float w1    = W_ih[row * 3 + 1];
    const float w2    = W_ih[row * 3 + 2];
    const float w12   = w1 + w2;
    const float braw  = b_ih[row] + b_hh[row];
    const float bfold = braw + w12 * blin;

    // Folded weights W'[row,c] = W_hh[row,c] + w12*W_lin[c]; this lane's
    // columns: c = k*64 + sub*4 + {0..3}, k = 0..31.
    float wreg[128];
    {
        const float* wrow = W_hh + (size_t)row * HDIM;
        #pragma unroll
        for (int k = 0; k < 32; ++k) {
            const int c = k * 64 + sub * 4;
            float4 wv = *reinterpret_cast<const float4*>(wrow + c);
            float4 lv = *reinterpret_cast<const float4*>(W_lin + c);
            wreg[k * 4 + 0] = wv.x + w12 * lv.x;
            wreg[k * 4 + 1] = wv.y + w12 * lv.y;
            wreg[k * 4 + 2] = wv.z + w12 * lv.z;
            wreg[k * 4 + 3] = wv.w + w12 * lv.w;
        }
    }

    __syncthreads();  // the only barrier

    float c_state = 0.0f;  // replicated across the wave's lanes

    // pull mapping: this thread pulls units pw*256 + j*64 + lane, j=0..3
    const int pbase = wave * 256 + lane;

    for (int t = 0; t < TSTEPS; ++t) {
        const int wb = t & 1;
        const int rb = wb ^ 1;  // holds h_{t-1} (valid for t>=1)

        float xterm;
        if (t == 0) {
            xterm = braw + w0 * s_lds[0] + w1 * s01 + w2 * s02;
        } else {
            xterm = bfold + w0 * s_lds[t];
        }

        float sum = 0.0f;
        if (t > 0) {
            float a0 = 0.0f, a1 = 0.0f, a2 = 0.0f, a3 = 0.0f;
            #pragma unroll
            for (int c = 0; c < 8; ++c) {
                // wait for chunk c of h_{t-1} (cheap LDS spin)
                while (__hip_atomic_load(&ready[rb][c], __ATOMIC_ACQUIRE,
                                         __HIP_MEMORY_SCOPE_WORKGROUP) != t) {}
                #pragma unroll
                for (int kk = 0; kk < 4; ++kk) {
                    const int k = c * 4 + kk;
                    const int col = k * 64 + sub * 4;
                    float4 h4 = *reinterpret_cast<const float4*>(&h_lds[rb][col]);
                    a0 += wreg[k * 4 + 0] * h4.x;
                    a1 += wreg[k * 4 + 1] * h4.y;
                    a2 += wreg[k * 4 + 2] * h4.z;
                    a3 += wreg[k * 4 + 3] * h4.w;
                }
            }
            // finalize y_{t-1}: all chunk flags == t confirmed above, so all
            // of the owner's per-wave ds_add contributions are visible.
            if (wave == 7 && wg == ((t - 1) & (NWG - 1)) && lane == 0) {
                out[t - 1] = y_acc[rb] + blin;
                y_acc[rb] = 0.0f;  // next reuse is step t+255: safe
            }
            sum = (a0 + a1) + (a2 + a3);
            sum += __shfl_xor(sum, 1);
            sum += __shfl_xor(sum, 2);
            sum += __shfl_xor(sum, 4);
            sum += __shfl_xor(sum, 8);
        }
        const float gate = sum + xterm;

        const float gi = __shfl(gate, 0);
        const float gf = __shfl(gate, 16);
        const float gg = __shfl(gate, 32);
        const float go = __shfl(gate, 48);
        c_state = sigmoidf_(gf) * c_state + sigmoidf_(gi) * tanhf(gg);
        const float h_new = sigmoidf_(go) * tanhf(c_state);

        // publish h_t[unit] as fused (tag | value)
        u64* hb = h_buf + (size_t)wb * HDIM;
        if (lane == 0) {
            const u64 p = ((u64)(unsigned)(t + 1) << 32) |
                          (u64)__float_as_uint(h_new);
            __hip_atomic_store(&hb[unit], p,
                               __ATOMIC_RELAXED, __HIP_MEMORY_SCOPE_AGENT);
        }

        // pull chunk `wave` of h_t: units pbase + 64j (coalesced per instr)
        const unsigned want = (unsigned)(t + 1);
        u64 v0, v1, v2, v3;
        for (;;) {
            v0 = __hip_atomic_load(&hb[pbase +   0], __ATOMIC_RELAXED, __HIP_MEMORY_SCOPE_AGENT);
            v1 = __hip_atomic_load(&hb[pbase +  64], __ATOMIC_RELAXED, __HIP_MEMORY_SCOPE_AGENT);
            v2 = __hip_atomic_load(&hb[pbase + 128], __ATOMIC_RELAXED, __HIP_MEMORY_SCOPE_AGENT);
            v3 = __hip_atomic_load(&hb[pbase + 192], __ATOMIC_RELAXED, __HIP_MEMORY_SCOPE_AGENT);
            if ((unsigned)(v0 >> 32) == want && (unsigned)(v1 >> 32) == want &&
                (unsigned)(v2 >> 32) == want && (unsigned)(v3 >> 32) == want)
                break;
            __builtin_amdgcn_s_sleep(2);  // throttle: ~128 cycles
        }
        const float f0 = __uint_as_float((unsigned)v0);
        const float f1 = __uint_as_float((unsigned)v1);
        const float f2 = __uint_as_float((unsigned)v2);
        const float f3 = __uint_as_float((unsigned)v3);
        h_lds[wb][pbase +   0] = f0;
        h_lds[wb][pbase +  64] = f1;
        h_lds[wb][pbase + 128] = f2;
        h_lds[wb][pbase + 192] = f3;

        // y_t partial for owner WG, from registers (off critical path)
        if (wg == (t & (NWG - 1))) {
            float yp = f0 * wlin_lds[pbase +   0] +
                       f1 * wlin_lds[pbase +  64] +
                       f2 * wlin_lds[pbase + 128] +
                       f3 * wlin_lds[pbase + 192];
            yp += __shfl_xor(yp, 1);
            yp += __shfl_xor(yp, 2);
            yp += __shfl_xor(yp, 4);
            yp += __shfl_xor(yp, 8);
            yp += __shfl_xor(yp, 16);
            yp += __shfl_xor(yp, 32);
            if (lane == 0) atomicAdd(&y_acc[wb], yp);
        }

        // chunk-ready flag (release: orders LDS writes + ds_add above)
        if (lane == 0) {
            __hip_atomic_store(&ready[wb][wave], t + 1,
                               __ATOMIC_RELEASE, __HIP_MEMORY_SCOPE_WORKGROUP);
        }
    }

    // final y_{T-1} (owner = (T-1) % 256 = 255, wave 7)
    if (wg == ((TSTEPS - 1) & (NWG - 1)) && wave == 7) {
        const int p = (TSTEPS - 1) & 1;
        #pragma unroll
        for (int c = 0; c < 8; ++c) {
            while (__hip_atomic_load(&ready[p][c], __ATOMIC_ACQUIRE,
                                     __HIP_MEMORY_SCOPE_WORKGROUP) != TSTEPS) {}
        }
        if (lane == 0) out[TSTEPS - 1] = y_acc[p] + blin;
    }
}

extern "C" void kernel_launch(void* const* d_in, const int* in_sizes, int n_in,
                              void* d_out, int out_size, void* d_ws, size_t ws_size,
                              hipStream_t stream) {
    const float* src   = (const float*)d_in[0];
    const float* W_ih  = (const float*)d_in[1];
    const float* W_hh  = (const float*)d_in[2];
    const float* b_ih  = (const float*)d_in[3];
    const float* b_hh  = (const float*)d_in[4];
    const float* W_lin = (const float*)d_in[5];
    const float* b_lin = (const float*)d_in[6];
    float* out = (float*)d_out;

    // ws: [0, 32 KiB) = h_buf: 2 (parity) x 2048 x 8 B packed tag|value.
    // Cleared every launch so stale tags from a previous replay can't match.
    u64* h_buf = (u64*)d_ws;
    hipMemsetAsync(d_ws, 0, 2 * HDIM * sizeof(u64), stream);

    void* args[] = { &src, &W_ih, &W_hh, &b_ih, &b_hh, &W_lin, &b_lin,
                     &out, &h_buf };
    hipLaunchCooperativeKernel((const void*)weld_lstm_persistent,
                               dim3(NWG), dim3(NTH), args, 0, stream);
}

// Round 4
// 24209.373 us; speedup vs baseline: 1.3910x; 1.3910x over previous
//
#include <hip/hip_runtime.h>
#include <math.h>

// Persistent cooperative LSTM: 256 WGs x 512 threads, 1 WG/CU.
// WG w owns hidden units [8w, 8w+8). wave u = unit, 16-lane group g = gate.
// Folded weights W' = W_hh + (w1+w2) (x) W_lin in regs (128/thread).
//
// Protocol (minimal coherence trips):
//   producer lane0 of each wave: ONE agent-scope store of packed
//     ((t+1)<<32 | f32bits(h_t[unit])) to h_buf[t&1][unit].
//   every thread polls 4 coalesced units (unit = wave*256+lane+64j) until
//     tag == t+1 (s_sleep-throttled), writes them to h_lds[t&1],
//   ONE __syncthreads, then next step's matvec reads h_lds.
// Tag t+1 is unique to (step t, parity t&1): reuse at t+2 writes tag t+3;
// pulls accept only the exact tag, so no ABA across the double buffer.
//
// y_t: pull phase computes per-wave partial dot(W_lin, h_t) from registers
// (owner WG only), ds_add into y_acc; owner's wave 7 writes out[t] next step
// (after the barrier), then clears y_acc. Next write is step t+256: safe.

#define HDIM 2048
#define TSTEPS 4096
#define NWG 256
#define NTH 512  // 8 waves

typedef unsigned long long u64;

__device__ __forceinline__ float sigmoidf_(float x) {
    return 1.0f / (1.0f + expf(-x));
}

__global__ __launch_bounds__(NTH, 2)
void weld_lstm_persistent(const float* __restrict__ src,
                          const float* __restrict__ W_ih,
                          const float* __restrict__ W_hh,
                          const float* __restrict__ b_ih,
                          const float* __restrict__ b_hh,
                          const float* __restrict__ W_lin,
                          const float* __restrict__ b_lin,
                          float* __restrict__ out,
                          u64* __restrict__ h_buf)
{
    __shared__ float h_lds[2][HDIM];   // h_lds[t&1] holds h_t
    __shared__ float s_lds[TSTEPS];    // src[0,t,0]
    __shared__ float wlin_lds[HDIM];
    __shared__ float y_acc;

    const int wg   = blockIdx.x;       // 0..255
    const int tid  = threadIdx.x;      // 0..511
    const int wave = tid >> 6;         // 0..7
    const int lane = tid & 63;
    const int g    = lane >> 4;        // gate 0..3 (i,f,g,o)
    const int sub  = lane & 15;        // column-slice within row
    const int unit = wg * 8 + wave;
    const int row  = g * HDIM + unit;

    // ---- one-time init ----
    for (int i = tid; i < TSTEPS; i += NTH) s_lds[i] = src[3 * i];
    for (int i = tid; i < HDIM;   i += NTH) wlin_lds[i] = W_lin[i];
    if (tid == 0) y_acc = 0.0f;

    const float s01  = src[1];
    const float s02  = src[2];
    const float blin = b_lin[0];

    const float w0    = W_ih[row * 3 + 0];
    const float w1    = W_ih[row * 3 + 1];
    const float w2    = W_ih[row * 3 + 2];
    const float w12   = w1 + w2;
    const float braw  = b_ih[row] + b_hh[row];
    const float bfold = braw + w12 * blin;

    // Folded weights W'[row,c] = W_hh[row,c] + w12*W_lin[c]; this lane's
    // columns: c = k*64 + sub*4 + {0..3}, k = 0..31.
    float wreg[128];
    {
        const float* wrow = W_hh + (size_t)row * HDIM;
        #pragma unroll
        for (int k = 0; k < 32; ++k) {
            const int c = k * 64 + sub * 4;
            float4 wv = *reinterpret_cast<const float4*>(wrow + c);
            float4 lv = *reinterpret_cast<const float4*>(W_lin + c);
            wreg[k * 4 + 0] = wv.x + w12 * lv.x;
            wreg[k * 4 + 1] = wv.y + w12 * lv.y;
            wreg[k * 4 + 2] = wv.z + w12 * lv.z;
            wreg[k * 4 + 3] = wv.w + w12 * lv.w;
        }
    }

    __syncthreads();

    float c_state = 0.0f;  // replicated across the wave's lanes

    const int pbase = wave * 256 + lane;  // pull mapping (coalesced)
    const float wl0 = wlin_lds[pbase +   0];
    const float wl1 = wlin_lds[pbase +  64];
    const float wl2 = wlin_lds[pbase + 128];
    const float wl3 = wlin_lds[pbase + 192];

    for (int t = 0; t < TSTEPS; ++t) {
        const int wb = t & 1;       // buffer receiving h_t
        const int rb = wb ^ 1;      // buffer holding h_{t-1} (t>=1)

        float xterm;
        if (t == 0) {
            xterm = braw + w0 * s_lds[0] + w1 * s01 + w2 * s02;
        } else {
            xterm = bfold + w0 * s_lds[t];
        }

        float sum = 0.0f;
        if (t > 0) {
            float a0 = 0.0f, a1 = 0.0f, a2 = 0.0f, a3 = 0.0f;
            #pragma unroll
            for (int k = 0; k < 32; ++k) {
                const int col = k * 64 + sub * 4;
                float4 h4 = *reinterpret_cast<const float4*>(&h_lds[rb][col]);
                a0 += wreg[k * 4 + 0] * h4.x;
                a1 += wreg[k * 4 + 1] * h4.y;
                a2 += wreg[k * 4 + 2] * h4.z;
                a3 += wreg[k * 4 + 3] * h4.w;
            }
            sum = (a0 + a1) + (a2 + a3);
            sum += __shfl_xor(sum, 1);
            sum += __shfl_xor(sum, 2);
            sum += __shfl_xor(sum, 4);
            sum += __shfl_xor(sum, 8);
        }

        // finalize y_{t-1}: owner of step t-1, after the iter-(t-1) barrier
        if (t > 0 && wg == ((t - 1) & (NWG - 1)) && wave == 7 && lane == 0) {
            out[t - 1] = y_acc + blin;
            y_acc = 0.0f;  // next partials for this WG arrive at step t+255
        }

        const float gate = sum + xterm;
        const float gi = __shfl(gate, 0);
        const float gf = __shfl(gate, 16);
        const float gg = __shfl(gate, 32);
        const float go = __shfl(gate, 48);
        c_state = sigmoidf_(gf) * c_state + sigmoidf_(gi) * tanhf(gg);
        const float h_new = sigmoidf_(go) * tanhf(c_state);

        // publish h_t[unit]: single fused (tag | value) store
        u64* hb = h_buf + (size_t)wb * HDIM;
        if (lane == 0) {
            const u64 p = ((u64)(unsigned)(t + 1) << 32) |
                          (u64)__float_as_uint(h_new);
            __hip_atomic_store(&hb[unit], p,
                               __ATOMIC_RELAXED, __HIP_MEMORY_SCOPE_AGENT);
        }

        // pull 4 coalesced units of h_t (512 B contiguous per wave per instr)
        const unsigned want = (unsigned)(t + 1);
        u64 v0, v1, v2, v3;
        for (;;) {
            v0 = __hip_atomic_load(&hb[pbase +   0], __ATOMIC_RELAXED, __HIP_MEMORY_SCOPE_AGENT);
            v1 = __hip_atomic_load(&hb[pbase +  64], __ATOMIC_RELAXED, __HIP_MEMORY_SCOPE_AGENT);
            v2 = __hip_atomic_load(&hb[pbase + 128], __ATOMIC_RELAXED, __HIP_MEMORY_SCOPE_AGENT);
            v3 = __hip_atomic_load(&hb[pbase + 192], __ATOMIC_RELAXED, __HIP_MEMORY_SCOPE_AGENT);
            if ((unsigned)(v0 >> 32) == want && (unsigned)(v1 >> 32) == want &&
                (unsigned)(v2 >> 32) == want && (unsigned)(v3 >> 32) == want)
                break;
            __builtin_amdgcn_s_sleep(1);  // ~64 cycles
        }
        const float f0 = __uint_as_float((unsigned)v0);
        const float f1 = __uint_as_float((unsigned)v1);
        const float f2 = __uint_as_float((unsigned)v2);
        const float f3 = __uint_as_float((unsigned)v3);
        h_lds[wb][pbase +   0] = f0;
        h_lds[wb][pbase +  64] = f1;
        h_lds[wb][pbase + 128] = f2;
        h_lds[wb][pbase + 192] = f3;

        // y_t partials from registers (owner WG only; off critical path)
        if (wg == (t & (NWG - 1))) {
            float yp = f0 * wl0 + f1 * wl1 + f2 * wl2 + f3 * wl3;
            yp += __shfl_xor(yp, 1);
            yp += __shfl_xor(yp, 2);
            yp += __shfl_xor(yp, 4);
            yp += __shfl_xor(yp, 8);
            yp += __shfl_xor(yp, 16);
            yp += __shfl_xor(yp, 32);
            if (lane == 0) atomicAdd(&y_acc, yp);
        }

        __syncthreads();  // h_lds[wb] complete; also orders y_acc partials
    }

    // final y_{T-1}: owner wg = 255, partials landed before the last barrier
    if (wg == ((TSTEPS - 1) & (NWG - 1)) && wave == 7 && lane == 0) {
        out[TSTEPS - 1] = y_acc + blin;
    }
}

extern "C" void kernel_launch(void* const* d_in, const int* in_sizes, int n_in,
                              void* d_out, int out_size, void* d_ws, size_t ws_size,
                              hipStream_t stream) {
    const float* src   = (const float*)d_in[0];
    const float* W_ih  = (const float*)d_in[1];
    const float* W_hh  = (const float*)d_in[2];
    const float* b_ih  = (const float*)d_in[3];
    const float* b_hh  = (const float*)d_in[4];
    const float* W_lin = (const float*)d_in[5];
    const float* b_lin = (const float*)d_in[6];
    float* out = (float*)d_out;

    // ws: [0, 32 KiB) = h_buf: 2 (parity) x 2048 x 8 B packed tag|value.
    // Cleared every launch so stale tags from a previous replay can't match.
    u64* h_buf = (u64*)d_ws;
    hipMemsetAsync(d_ws, 0, 2 * HDIM * sizeof(u64), stream);

    void* args[] = { &src, &W_ih, &W_hh, &b_ih, &b_hh, &W_lin, &b_lin,
                     &out, &h_buf };
    hipLaunchCooperativeKernel((const void*)weld_lstm_persistent,
                               dim3(NWG), dim3(NTH), args, 0, stream);
}